// Round 1
// baseline (682.984 us; speedup 1.0000x reference)
//
#include <hip/hip_runtime.h>
#include <hip/hip_bf16.h>
#include <math.h>

// Problem constants
#define B_ 4
#define NQ 5440          // 64*64 + 32*32 + 16*16 + 8*8
#define M_ROWS (B_ * NQ) // 21760
#define EMBED_ 256
#define NH 8
#define NL 4
#define NP 4
#define HD 32

__constant__ int c_dummy; // keep toolchain happy

// ---------------- Tiled fp32 GEMM with bias: C[M,N] = A[M,K] @ W[K,N] + bias[N]
// BM=BN=64, BK=16, 256 threads, 4x4 micro-tile per thread.
__global__ __launch_bounds__(256) void gemm_bias_kernel(
    const float* __restrict__ A, const float* __restrict__ W,
    const float* __restrict__ bias, float* __restrict__ C,
    int M, int N, int K) {
  constexpr int BM = 64, BN = 64, BK = 16, TM = 4, TN = 4;
  __shared__ float As[BK][BM + 1];
  __shared__ float Ws[BK][BN + 1];
  const int bm = blockIdx.y * BM;
  const int bn = blockIdx.x * BN;
  const int tid = threadIdx.x;
  const int tx = tid & 15;   // N direction
  const int ty = tid >> 4;   // M direction
  float acc[TM][TN] = {};
  for (int k0 = 0; k0 < K; k0 += BK) {
    // Load A tile (BM x BK): consecutive tid -> consecutive k
    for (int i = tid; i < BM * BK; i += 256) {
      int m = i >> 4;        // /BK
      int k = i & 15;        // %BK
      int gm = bm + m;
      float a = 0.f;
      if (gm < M) a = A[(size_t)gm * K + k0 + k];
      As[k][m] = a;
    }
    // Load W tile (BK x BN): consecutive tid -> consecutive n (coalesced)
    for (int i = tid; i < BK * BN; i += 256) {
      int k = i >> 6;        // /BN
      int n = i & 63;        // %BN
      int gn = bn + n;
      float w = 0.f;
      if (gn < N) w = W[(size_t)(k0 + k) * N + gn];
      Ws[k][n] = w;
    }
    __syncthreads();
#pragma unroll
    for (int k = 0; k < BK; ++k) {
      float ar[TM], wr[TN];
#pragma unroll
      for (int i = 0; i < TM; ++i) ar[i] = As[k][ty * TM + i];
#pragma unroll
      for (int j = 0; j < TN; ++j) wr[j] = Ws[k][tx * TN + j];
#pragma unroll
      for (int i = 0; i < TM; ++i)
#pragma unroll
        for (int j = 0; j < TN; ++j) acc[i][j] += ar[i] * wr[j];
    }
    __syncthreads();
  }
#pragma unroll
  for (int i = 0; i < TM; ++i) {
    int gm = bm + ty * TM + i;
    if (gm >= M) continue;
#pragma unroll
    for (int j = 0; j < TN; ++j) {
      int gn = bn + tx * TN + j;
      if (gn < N) C[(size_t)gm * N + gn] = acc[i][j] + bias[gn];
    }
  }
}

// ---------------- Softmax over groups of 16 (one thread per group)
__global__ __launch_bounds__(256) void softmax16_kernel(float* __restrict__ aw, int ngroups) {
  int i = blockIdx.x * blockDim.x + threadIdx.x;
  if (i >= ngroups) return;
  float* p = aw + (size_t)i * 16;
  float v[16];
  float m = -1e30f;
#pragma unroll
  for (int j = 0; j < 16; ++j) { v[j] = p[j]; m = fmaxf(m, v[j]); }
  float s = 0.f;
#pragma unroll
  for (int j = 0; j < 16; ++j) { v[j] = __expf(v[j] - m); s += v[j]; }
  float inv = 1.f / s;
#pragma unroll
  for (int j = 0; j < 16; ++j) p[j] = v[j] * inv;
}

// ---------------- Deformable sampling + weighted accumulation
// grid = B*NQ blocks, 256 threads = 8 heads x 32 dims.
// v: (B, NQ, NH, HD)  refp: (B,NQ,NL,2)  off: (B*NQ, 256)  aw: (B*NQ, 128)
// out: (B*NQ, 256) = (B,NQ,NH,HD)
__global__ __launch_bounds__(256) void sample_kernel(
    const float* __restrict__ v, const float* __restrict__ refp,
    const float* __restrict__ off, const float* __restrict__ aw,
    float* __restrict__ out) {
  const int bq = blockIdx.x;          // b*NQ + q
  const int b  = bq / NQ;
  const int h  = threadIdx.x >> 5;
  const int d  = threadIdx.x & 31;

  const int HS[NL]      = {64, 32, 16, 8};
  const int WS[NL]      = {64, 32, 16, 8};
  const int LVL_OFF[NL] = {0, 4096, 5120, 5376};

  float acc = 0.f;
#pragma unroll
  for (int l = 0; l < NL; ++l) {
    const float rx = refp[(size_t)bq * (NL * 2) + l * 2 + 0];
    const float ry = refp[(size_t)bq * (NL * 2) + l * 2 + 1];
    const int H = HS[l], W = WS[l];
    const size_t vbase = ((size_t)b * NQ + LVL_OFF[l]) * (NH * HD) + h * HD + d;
#pragma unroll
    for (int p = 0; p < NP; ++p) {
      const float ox = off[(size_t)bq * 256 + h * 32 + l * 8 + p * 2 + 0];
      const float oy = off[(size_t)bq * 256 + h * 32 + l * 8 + p * 2 + 1];
      const float a  = aw[(size_t)bq * 128 + h * 16 + l * 4 + p];
      // loc = ref + off/ (W,H); px = loc_x*W - 0.5 = rx*W + ox - 0.5
      const float px = rx * (float)W + ox - 0.5f;
      const float py = ry * (float)H + oy - 0.5f;
      const float x0f = floorf(px), y0f = floorf(py);
      const int x0 = (int)x0f, y0 = (int)y0f;
      const int x1 = x0 + 1, y1 = y0 + 1;
      const float wx = px - x0f, wy = py - y0f;
      const bool vx0 = (x0 >= 0) & (x0 < W);
      const bool vx1 = (x1 >= 0) & (x1 < W);
      const bool vy0 = (y0 >= 0) & (y0 < H);
      const bool vy1 = (y1 >= 0) & (y1 < H);
      float s = 0.f;
      if (vy0) {
        const size_t row = vbase + (size_t)(y0 * W) * (NH * HD);
        if (vx0) s += (1.f - wx) * (1.f - wy) * v[row + (size_t)x0 * (NH * HD)];
        if (vx1) s += wx * (1.f - wy) * v[row + (size_t)x1 * (NH * HD)];
      }
      if (vy1) {
        const size_t row = vbase + (size_t)(y1 * W) * (NH * HD);
        if (vx0) s += (1.f - wx) * wy * v[row + (size_t)x0 * (NH * HD)];
        if (vx1) s += wx * wy * v[row + (size_t)x1 * (NH * HD)];
      }
      acc += a * s;
    }
  }
  out[(size_t)bq * 256 + h * HD + d] = acc;
}

extern "C" void kernel_launch(void* const* d_in, const int* in_sizes, int n_in,
                              void* d_out, int out_size, void* d_ws, size_t ws_size,
                              hipStream_t stream) {
  const float* query        = (const float*)d_in[0];  // (B,NQ,256)
  const float* value        = (const float*)d_in[1];  // (B,NQ,256)
  const float* refp         = (const float*)d_in[2];  // (B,NQ,4,2)
  const float* value_proj_w = (const float*)d_in[3];  // (256,256)
  const float* value_proj_b = (const float*)d_in[4];  // (256,)
  const float* offsets_w    = (const float*)d_in[5];  // (256,256)
  const float* offsets_b    = (const float*)d_in[6];  // (256,)
  const float* attn_w_w     = (const float*)d_in[7];  // (256,128)
  const float* attn_w_b     = (const float*)d_in[8];  // (128,)
  const float* out_w        = (const float*)d_in[9];  // (256,256)
  const float* out_b        = (const float*)d_in[10]; // (256,)
  float* out = (float*)d_out;

  const int M = M_ROWS;  // 21760
  float* ws_v    = (float*)d_ws;                 // M*256
  float* ws_off  = ws_v   + (size_t)M * 256;     // M*256
  float* ws_aw   = ws_off + (size_t)M * 256;     // M*128
  float* ws_attn = ws_aw  + (size_t)M * 128;     // M*256

  dim3 blk(256);
  // 1) value projection: v = value @ value_proj_w + b
  gemm_bias_kernel<<<dim3(256 / 64, M / 64), blk, 0, stream>>>(
      value, value_proj_w, value_proj_b, ws_v, M, 256, 256);
  // 2) offsets: off = query @ offsets_w + b
  gemm_bias_kernel<<<dim3(256 / 64, M / 64), blk, 0, stream>>>(
      query, offsets_w, offsets_b, ws_off, M, 256, 256);
  // 3) attention weights: aw = query @ attn_w_w + b
  gemm_bias_kernel<<<dim3(128 / 64, M / 64), blk, 0, stream>>>(
      query, attn_w_w, attn_w_b, ws_aw, M, 128, 256);
  // 4) softmax over last 16
  {
    int ngroups = M * NH;
    softmax16_kernel<<<(ngroups + 255) / 256, blk, 0, stream>>>(ws_aw, ngroups);
  }
  // 5) deformable bilinear sampling + weighted sum
  sample_kernel<<<M, blk, 0, stream>>>(ws_v, refp, ws_off, ws_aw, ws_attn);
  // 6) output projection: out = attn @ out_w + out_b
  gemm_bias_kernel<<<dim3(256 / 64, M / 64), blk, 0, stream>>>(
      ws_attn, out_w, out_b, out, M, 256, 256);
}

// Round 2
// 281.148 us; speedup vs baseline: 2.4293x; 2.4293x over previous
//
#include <hip/hip_runtime.h>
#include <hip/hip_bf16.h>
#include <math.h>

// Problem constants
#define B_ 4
#define NQ 5440          // 64*64 + 32*32 + 16*16 + 8*8
#define M_ROWS (B_ * NQ) // 21760
#define NH 8
#define NL 4
#define NP 4
#define HD 32

typedef __attribute__((ext_vector_type(8))) short bf16x8; // 8 bf16 (4 VGPRs)
typedef __attribute__((ext_vector_type(4))) float f32x4;  // 4 fp32

static __device__ __forceinline__ short f2bf(float f) {
  union { float f; unsigned u; } in; in.f = f;
  // round-to-nearest-even bf16
  unsigned r = (in.u + 0x7fffu + ((in.u >> 16) & 1u)) >> 16;
  return (short)r;
}

// ---------------- bf16 MFMA GEMM with fp32 bias: C[M,N] = bf16(A[M,K]) @ bf16(W[K,N]) + bias[N]
// BM=BN=64, BK=32; 256 threads = 4 waves, each wave computes a 32x32 tile
// via 2x2 of mfma_f32_16x16x32_bf16. fp32 accumulate. M % 64 == 0, N % 64 == 0, K % 32 == 0.
__global__ __launch_bounds__(256) void mfma_gemm_bias(
    const float* __restrict__ A, const float* __restrict__ W,
    const float* __restrict__ bias, float* __restrict__ C,
    int N, int K) {
  // +8 pad per row (stride 40 bf16 = 80 B) -> max 2-way bank aliasing (free)
  __shared__ short As[64 * 40];
  __shared__ short Bs[64 * 40];
  const int t = threadIdx.x;
  const int lane = t & 63, wid = t >> 6;
  const int qd = lane >> 4, l16 = lane & 15;
  const int wm = (wid >> 1) * 32, wn = (wid & 1) * 32;
  const int bm = blockIdx.y * 64, bn = blockIdx.x * 64;

  f32x4 acc[2][2] = {};

  const int am = t >> 2, ak = (t & 3) * 8;   // A-stage: m=am, k=ak..ak+7
  const int bnl = t & 63, bk = (t >> 6) * 8; // B-stage: n=bnl, k=bk..bk+7

  for (int k0 = 0; k0 < K; k0 += 32) {
    // global loads first (overlap with previous iteration's MFMA)
    const float* ap = A + (size_t)(bm + am) * K + k0 + ak;
    const float4 a0 = *(const float4*)ap;
    const float4 a1 = *(const float4*)(ap + 4);
    bf16x8 av;
    av[0] = f2bf(a0.x); av[1] = f2bf(a0.y); av[2] = f2bf(a0.z); av[3] = f2bf(a0.w);
    av[4] = f2bf(a1.x); av[5] = f2bf(a1.y); av[6] = f2bf(a1.z); av[7] = f2bf(a1.w);
    const float* bp = W + (size_t)(k0 + bk) * N + bn + bnl;
    bf16x8 bv;
#pragma unroll
    for (int i = 0; i < 8; ++i) bv[i] = f2bf(bp[(size_t)i * N]);
    __syncthreads(); // previous iteration's LDS reads done
    *(bf16x8*)(As + am * 40 + ak)  = av;
    *(bf16x8*)(Bs + bnl * 40 + bk) = bv;
    __syncthreads();
    // fragments: A[m=l16][k=qd*8+j]; B stored transposed [n][k]
    const bf16x8 af0 = *(const bf16x8*)(As + (wm + l16) * 40 + qd * 8);
    const bf16x8 af1 = *(const bf16x8*)(As + (wm + 16 + l16) * 40 + qd * 8);
    const bf16x8 bf0 = *(const bf16x8*)(Bs + (wn + l16) * 40 + qd * 8);
    const bf16x8 bf1 = *(const bf16x8*)(Bs + (wn + 16 + l16) * 40 + qd * 8);
    acc[0][0] = __builtin_amdgcn_mfma_f32_16x16x32_bf16(af0, bf0, acc[0][0], 0, 0, 0);
    acc[0][1] = __builtin_amdgcn_mfma_f32_16x16x32_bf16(af0, bf1, acc[0][1], 0, 0, 0);
    acc[1][0] = __builtin_amdgcn_mfma_f32_16x16x32_bf16(af1, bf0, acc[1][0], 0, 0, 0);
    acc[1][1] = __builtin_amdgcn_mfma_f32_16x16x32_bf16(af1, bf1, acc[1][1], 0, 0, 0);
  }
  // epilogue: C/D layout col=lane&15, row=(lane>>4)*4+reg  [m89-verified]
  const float b0 = bias[bn + wn + l16];
  const float b1 = bias[bn + wn + 16 + l16];
#pragma unroll
  for (int mi = 0; mi < 2; ++mi) {
#pragma unroll
    for (int r = 0; r < 4; ++r) {
      const int gm = bm + wm + mi * 16 + qd * 4 + r;
      float* crow = C + (size_t)gm * N + bn + wn;
      crow[l16]      = acc[mi][0][r] + b0;
      crow[16 + l16] = acc[mi][1][r] + b1;
    }
  }
}

// ---------------- Fused softmax + deformable bilinear sampling
// 4 queries per block, 64 threads per query = 8 heads x 8 lanes x float4 (4 dims).
// v: (B,NQ,NH,HD)  refp: (B,NQ,NL,2)  off: (B*NQ,256)  aw_in: (B*NQ,128) raw logits
// out: (B*NQ, 256)
__global__ __launch_bounds__(256) void sample_fused_kernel(
    const float* __restrict__ v, const float* __restrict__ refp,
    const float* __restrict__ off, const float* __restrict__ aw_in,
    float* __restrict__ out) {
  __shared__ float s_off[4 * 256];
  __shared__ float s_aw[4 * 128];
  const int t = threadIdx.x;
  const int q0 = blockIdx.x * 4;

  // stage offsets (1024 floats) + attn logits (512 floats), coalesced float4
  ((float4*)s_off)[t] = ((const float4*)(off + (size_t)q0 * 256))[t];
  if (t < 128) ((float4*)s_aw)[t] = ((const float4*)(aw_in + (size_t)q0 * 128))[t];
  __syncthreads();

  // softmax: 32 groups of 16 (4 queries x 8 heads), one thread each
  if (t < 32) {
    float* p = s_aw + t * 16;
    float m = -1e30f;
#pragma unroll
    for (int j = 0; j < 16; ++j) m = fmaxf(m, p[j]);
    float e[16]; float s = 0.f;
#pragma unroll
    for (int j = 0; j < 16; ++j) { e[j] = __expf(p[j] - m); s += e[j]; }
    const float inv = 1.f / s;
#pragma unroll
    for (int j = 0; j < 16; ++j) p[j] = e[j] * inv;
  }
  __syncthreads();

  const int ql = t >> 6;
  const int bq = q0 + ql;
  const int b  = bq / NQ;
  const int lane = t & 63;
  const int h  = lane >> 3;
  const int d4 = (lane & 7) * 4;

  const int HS[NL]      = {64, 32, 16, 8};
  const int LVL_OFF[NL] = {0, 4096, 5120, 5376};

  f32x4 acc = {0.f, 0.f, 0.f, 0.f};
#pragma unroll
  for (int l = 0; l < NL; ++l) {
    const int H = HS[l], W = HS[l];
    const float rx = refp[(size_t)bq * 8 + l * 2 + 0];
    const float ry = refp[(size_t)bq * 8 + l * 2 + 1];
    const float* vb = v + (size_t)(b * NQ + LVL_OFF[l]) * 256 + h * HD + d4;
#pragma unroll
    for (int p = 0; p < NP; ++p) {
      const float ox = s_off[ql * 256 + h * 32 + l * 8 + p * 2 + 0];
      const float oy = s_off[ql * 256 + h * 32 + l * 8 + p * 2 + 1];
      const float a  = s_aw[ql * 128 + h * 16 + l * 4 + p];
      const float px = rx * (float)W + ox - 0.5f;
      const float py = ry * (float)H + oy - 0.5f;
      const float x0f = floorf(px), y0f = floorf(py);
      const int x0 = (int)x0f, y0 = (int)y0f;
      const int x1 = x0 + 1, y1 = y0 + 1;
      const float wx = px - x0f, wy = py - y0f;
      const bool vx0 = (x0 >= 0) & (x0 < W);
      const bool vx1 = (x1 >= 0) & (x1 < W);
      const bool vy0 = (y0 >= 0) & (y0 < H);
      const bool vy1 = (y1 >= 0) & (y1 < H);
      f32x4 s = {0.f, 0.f, 0.f, 0.f};
      if (vy0) {
        const float* row = vb + (size_t)(y0 * W) * 256;
        if (vx0) { const f32x4 c = *(const f32x4*)(row + (size_t)x0 * 256); s += ((1.f - wx) * (1.f - wy)) * c; }
        if (vx1) { const f32x4 c = *(const f32x4*)(row + (size_t)x1 * 256); s += (wx * (1.f - wy)) * c; }
      }
      if (vy1) {
        const float* row = vb + (size_t)(y1 * W) * 256;
        if (vx0) { const f32x4 c = *(const f32x4*)(row + (size_t)x0 * 256); s += ((1.f - wx) * wy) * c; }
        if (vx1) { const f32x4 c = *(const f32x4*)(row + (size_t)x1 * 256); s += (wx * wy) * c; }
      }
      acc += a * s;
    }
  }
  *(f32x4*)(out + (size_t)bq * 256 + h * HD + d4) = acc;
}

extern "C" void kernel_launch(void* const* d_in, const int* in_sizes, int n_in,
                              void* d_out, int out_size, void* d_ws, size_t ws_size,
                              hipStream_t stream) {
  const float* query        = (const float*)d_in[0];  // (B,NQ,256)
  const float* value        = (const float*)d_in[1];  // (B,NQ,256)
  const float* refp         = (const float*)d_in[2];  // (B,NQ,4,2)
  const float* value_proj_w = (const float*)d_in[3];  // (256,256)
  const float* value_proj_b = (const float*)d_in[4];  // (256,)
  const float* offsets_w    = (const float*)d_in[5];  // (256,256)
  const float* offsets_b    = (const float*)d_in[6];  // (256,)
  const float* attn_w_w     = (const float*)d_in[7];  // (256,128)
  const float* attn_w_b     = (const float*)d_in[8];  // (128,)
  const float* out_w        = (const float*)d_in[9];  // (256,256)
  const float* out_b        = (const float*)d_in[10]; // (256,)
  float* out = (float*)d_out;

  const int M = M_ROWS;  // 21760, divisible by 64
  float* ws_v    = (float*)d_ws;                 // M*256
  float* ws_off  = ws_v   + (size_t)M * 256;     // M*256
  float* ws_aw   = ws_off + (size_t)M * 256;     // M*128 (raw logits)
  float* ws_attn = ws_aw  + (size_t)M * 128;     // M*256

  dim3 blk(256);
  // 1) value projection
  mfma_gemm_bias<<<dim3(256 / 64, M / 64), blk, 0, stream>>>(
      value, value_proj_w, value_proj_b, ws_v, 256, 256);
  // 2) offsets
  mfma_gemm_bias<<<dim3(256 / 64, M / 64), blk, 0, stream>>>(
      query, offsets_w, offsets_b, ws_off, 256, 256);
  // 3) attention logits
  mfma_gemm_bias<<<dim3(128 / 64, M / 64), blk, 0, stream>>>(
      query, attn_w_w, attn_w_b, ws_aw, 128, 256);
  // 4) fused softmax + sampling
  sample_fused_kernel<<<M / 4, blk, 0, stream>>>(ws_v, refp, ws_off, ws_aw, ws_attn);
  // 5) output projection
  mfma_gemm_bias<<<dim3(256 / 64, M / 64), blk, 0, stream>>>(
      ws_attn, out_w, out_b, out, 256, 256);
}

// Round 3
// 259.259 us; speedup vs baseline: 2.6344x; 1.0844x over previous
//
#include <hip/hip_runtime.h>
#include <hip/hip_bf16.h>
#include <math.h>

// Problem constants
#define B_ 4
#define NQ 5440          // 64*64 + 32*32 + 16*16 + 8*8
#define M_ROWS (B_ * NQ) // 21760
#define NH 8
#define NL 4
#define NP 4
#define HD 32

typedef __attribute__((ext_vector_type(8))) short bf16x8; // 8 bf16 (4 VGPRs)
typedef __attribute__((ext_vector_type(4))) short bf16x4; // 8 bytes
typedef __attribute__((ext_vector_type(4))) float f32x4;

static __device__ __forceinline__ unsigned short f2bf(float f) {
  union { float f; unsigned u; } v; v.f = f;
  unsigned r = (v.u + 0x7fffu + ((v.u >> 16) & 1u)) >> 16; // RNE
  return (unsigned short)r;
}
static __device__ __forceinline__ float bf2f(unsigned short b) {
  union { unsigned u; float f; } v; v.u = ((unsigned)b) << 16; return v.f;
}

// ---------------- fp32 -> bf16 elementwise (float4 in, bf16x4 out)
__global__ __launch_bounds__(256) void conv_bf16(
    const float* __restrict__ in, unsigned short* __restrict__ out, int n4) {
  int i = blockIdx.x * 256 + threadIdx.x;
  if (i >= n4) return;
  float4 f = ((const float4*)in)[i];
  bf16x4 o;
  o[0] = f2bf(f.x); o[1] = f2bf(f.y); o[2] = f2bf(f.z); o[3] = f2bf(f.w);
  ((bf16x4*)out)[i] = o;
}

// ---------------- weight prep: transpose + convert to bf16 W^T[n][k]; concat off+attn
__global__ __launch_bounds__(256) void prep_weights(
    const float* __restrict__ vpw, const float* __restrict__ offw,
    const float* __restrict__ attnw, const float* __restrict__ outw,
    const float* __restrict__ offb, const float* __restrict__ attnb,
    unsigned short* __restrict__ vp_t, unsigned short* __restrict__ q_t,
    unsigned short* __restrict__ out_t, float* __restrict__ biasq) {
  int id = blockIdx.x * 256 + threadIdx.x;
  if (id < 65536) {                       // vp_t[256][256]
    int n = id >> 8, k = id & 255;
    vp_t[id] = f2bf(vpw[k * 256 + n]);
  } else if (id < 163840) {               // q_t[384][256] = [off^T ; attn^T]
    int q = id - 65536; int n = q >> 8, k = q & 255;
    q_t[q] = f2bf(n < 256 ? offw[k * 256 + n] : attnw[k * 128 + (n - 256)]);
  } else if (id < 229376) {               // out_t[256][256]
    int o = id - 163840; int n = o >> 8, k = o & 255;
    out_t[o] = f2bf(outw[k * 256 + n]);
  } else if (id < 229760) {               // biasq[384]
    int j = id - 229376;
    biasq[j] = j < 256 ? offb[j] : attnb[j - 256];
  }
}

static __device__ __forceinline__ void store_c(float* p, float v) { *p = v; }
static __device__ __forceinline__ void store_c(unsigned short* p, float v) { *p = f2bf(v); }

// ---------------- m97-style bf16 MFMA GEMM: C[M,N] = A_bf16[M,K] @ Wt_bf16[N,K]^T + bias
// BM=BN=64, BK=32, 256 threads = 4 waves, wave = 32x32 via 2x2 mfma_16x16x32.
// K-loop: global_load_lds dwordx4 staging (lane-ordered LDS), ds_read_b128 frags, no VALU conv.
template <typename OUT_T>
__global__ __launch_bounds__(256) void mfma_gemm_lds(
    const unsigned short* __restrict__ A, const unsigned short* __restrict__ Wt,
    const float* __restrict__ bias, OUT_T* __restrict__ C, int N, int K) {
  __shared__ unsigned short As[64 * 32]; // [m][k], lane-ordered for global_load_lds
  __shared__ unsigned short Bs[64 * 32]; // [n][k]
  const int t = threadIdx.x;
  const int lane = t & 63, wid = t >> 6;
  const int qd = lane >> 4, l16 = lane & 15;
  const int wm = (wid >> 1) * 32, wn = (wid & 1) * 32;
  const int bm = blockIdx.y * 64, bn = blockIdx.x * 64;

  f32x4 acc[2][2] = {};

  // staging: thread t covers (row = t>>2, k = (t&3)*8), LDS offset = 16*t bytes
  const unsigned short* ag = A + (size_t)(bm + (t >> 2)) * K + (t & 3) * 8;
  const unsigned short* bg = Wt + (size_t)(bn + (t >> 2)) * K + (t & 3) * 8;
  unsigned short* as_b = As + (t & 192) * 8; // wave-uniform base; HW adds lane*16B
  unsigned short* bs_b = Bs + (t & 192) * 8;

  for (int k0 = 0; k0 < K; k0 += 32) {
    __syncthreads(); // previous iteration's ds_reads done
    __builtin_amdgcn_global_load_lds(
        (const __attribute__((address_space(1))) void*)(ag + k0),
        (__attribute__((address_space(3))) void*)as_b, 16, 0, 0);
    __builtin_amdgcn_global_load_lds(
        (const __attribute__((address_space(1))) void*)(bg + k0),
        (__attribute__((address_space(3))) void*)bs_b, 16, 0, 0);
    __syncthreads(); // drains vmcnt -> LDS valid
    const bf16x8 af0 = *(const bf16x8*)(As + (wm + l16) * 32 + qd * 8);
    const bf16x8 af1 = *(const bf16x8*)(As + (wm + 16 + l16) * 32 + qd * 8);
    const bf16x8 bf0 = *(const bf16x8*)(Bs + (wn + l16) * 32 + qd * 8);
    const bf16x8 bf1 = *(const bf16x8*)(Bs + (wn + 16 + l16) * 32 + qd * 8);
    acc[0][0] = __builtin_amdgcn_mfma_f32_16x16x32_bf16(af0, bf0, acc[0][0], 0, 0, 0);
    acc[0][1] = __builtin_amdgcn_mfma_f32_16x16x32_bf16(af0, bf1, acc[0][1], 0, 0, 0);
    acc[1][0] = __builtin_amdgcn_mfma_f32_16x16x32_bf16(af1, bf0, acc[1][0], 0, 0, 0);
    acc[1][1] = __builtin_amdgcn_mfma_f32_16x16x32_bf16(af1, bf1, acc[1][1], 0, 0, 0);
  }
  // C/D layout: col = lane&15, row = (lane>>4)*4 + reg  [m89-verified]
  const float b0 = bias[bn + wn + l16];
  const float b1 = bias[bn + wn + 16 + l16];
#pragma unroll
  for (int mi = 0; mi < 2; ++mi) {
#pragma unroll
    for (int r = 0; r < 4; ++r) {
      const int gm = bm + wm + mi * 16 + qd * 4 + r;
      OUT_T* crow = C + (size_t)gm * N + bn + wn;
      store_c(crow + l16,      acc[mi][0][r] + b0);
      store_c(crow + 16 + l16, acc[mi][1][r] + b1);
    }
  }
}

// ---------------- Fused softmax + deformable bilinear sampling (bf16 v, bf16 out)
// 4 queries/block, 64 threads/query = 8 heads x 8 lanes x 4 dims (bf16x4 gathers).
// offaw: (B*NQ, 384) fp32 — cols [0,256) offsets, [256,384) attn logits.
__global__ __launch_bounds__(256) void sample_fused_kernel(
    const unsigned short* __restrict__ v, const float* __restrict__ refp,
    const float* __restrict__ offaw, unsigned short* __restrict__ out) {
  __shared__ float s_off[4 * 8 * 36]; // stride 36: heads on distinct banks
  __shared__ float s_aw[4 * 8 * 20];  // stride 20: heads on distinct banks
  const int t = threadIdx.x;
  const int q0 = blockIdx.x * 4;

  { // stage offsets: 4 queries x 256 floats, float4/thread, padded scatter
    const int ql = t >> 6, c = (t & 63) * 4, h = c >> 5, r = c & 31;
    const float4 f = *(const float4*)(offaw + (size_t)(q0 + ql) * 384 + c);
    *(float4*)&s_off[ql * 288 + h * 36 + r] = f;
  }
  if (t < 128) { // stage attn logits: 4 x 128
    const int ql = t >> 5, c = (t & 31) * 4, h = c >> 4, r = c & 15;
    const float4 f = *(const float4*)(offaw + (size_t)(q0 + ql) * 384 + 256 + c);
    *(float4*)&s_aw[ql * 160 + h * 20 + r] = f;
  }
  __syncthreads();
  if (t < 32) { // softmax: 32 groups of 16 (4 queries x 8 heads)
    float* p = s_aw + (t >> 3) * 160 + (t & 7) * 20;
    float m = -1e30f;
#pragma unroll
    for (int j = 0; j < 16; ++j) m = fmaxf(m, p[j]);
    float e[16]; float s = 0.f;
#pragma unroll
    for (int j = 0; j < 16; ++j) { e[j] = __expf(p[j] - m); s += e[j]; }
    const float inv = 1.f / s;
#pragma unroll
    for (int j = 0; j < 16; ++j) p[j] = e[j] * inv;
  }
  __syncthreads();

  const int ql = t >> 6;
  const int bq = q0 + ql;
  const int b  = bq / NQ;
  const int lane = t & 63;
  const int h  = lane >> 3;
  const int d4 = (lane & 7) * 4;
  const float* so = s_off + ql * 288 + h * 36;
  const float* sa = s_aw + ql * 160 + h * 20;

  const int HS[NL]      = {64, 32, 16, 8};
  const int LVL_OFF[NL] = {0, 4096, 5120, 5376};

  f32x4 acc = {0.f, 0.f, 0.f, 0.f};
#pragma unroll
  for (int l = 0; l < NL; ++l) {
    const int H = HS[l], W = HS[l];
    const float rx = refp[(size_t)bq * 8 + l * 2 + 0];
    const float ry = refp[(size_t)bq * 8 + l * 2 + 1];
    const unsigned short* vb =
        v + (size_t)(b * NQ + LVL_OFF[l]) * 256 + h * HD + d4;
#pragma unroll
    for (int p = 0; p < NP; ++p) {
      const float ox = so[l * 8 + p * 2 + 0];
      const float oy = so[l * 8 + p * 2 + 1];
      const float a  = sa[l * 4 + p];
      const float px = rx * (float)W + ox - 0.5f;
      const float py = ry * (float)H + oy - 0.5f;
      const float x0f = floorf(px), y0f = floorf(py);
      const int x0 = (int)x0f, y0 = (int)y0f;
      const int x1 = x0 + 1, y1 = y0 + 1;
      const float wx = px - x0f, wy = py - y0f;
      const bool vx0 = (x0 >= 0) & (x0 < W);
      const bool vx1 = (x1 >= 0) & (x1 < W);
      const bool vy0 = (y0 >= 0) & (y0 < H);
      const bool vy1 = (y1 >= 0) & (y1 < H);
      f32x4 s = {0.f, 0.f, 0.f, 0.f};
      if (vy0) {
        const unsigned short* row = vb + (size_t)(y0 * W) * 256;
        if (vx0) {
          const bf16x4 c = *(const bf16x4*)(row + (size_t)x0 * 256);
          f32x4 cf = {bf2f((unsigned short)c[0]), bf2f((unsigned short)c[1]),
                      bf2f((unsigned short)c[2]), bf2f((unsigned short)c[3])};
          s += ((1.f - wx) * (1.f - wy)) * cf;
        }
        if (vx1) {
          const bf16x4 c = *(const bf16x4*)(row + (size_t)x1 * 256);
          f32x4 cf = {bf2f((unsigned short)c[0]), bf2f((unsigned short)c[1]),
                      bf2f((unsigned short)c[2]), bf2f((unsigned short)c[3])};
          s += (wx * (1.f - wy)) * cf;
        }
      }
      if (vy1) {
        const unsigned short* row = vb + (size_t)(y1 * W) * 256;
        if (vx0) {
          const bf16x4 c = *(const bf16x4*)(row + (size_t)x0 * 256);
          f32x4 cf = {bf2f((unsigned short)c[0]), bf2f((unsigned short)c[1]),
                      bf2f((unsigned short)c[2]), bf2f((unsigned short)c[3])};
          s += ((1.f - wx) * wy) * cf;
        }
        if (vx1) {
          const bf16x4 c = *(const bf16x4*)(row + (size_t)x1 * 256);
          f32x4 cf = {bf2f((unsigned short)c[0]), bf2f((unsigned short)c[1]),
                      bf2f((unsigned short)c[2]), bf2f((unsigned short)c[3])};
          s += (wx * wy) * cf;
        }
      }
      acc += a * s;
    }
  }
  unsigned short* op = out + (size_t)bq * 256 + h * HD + d4;
  bf16x4 ov;
  ov[0] = f2bf(acc[0]); ov[1] = f2bf(acc[1]);
  ov[2] = f2bf(acc[2]); ov[3] = f2bf(acc[3]);
  *(bf16x4*)op = ov;
}

extern "C" void kernel_launch(void* const* d_in, const int* in_sizes, int n_in,
                              void* d_out, int out_size, void* d_ws, size_t ws_size,
                              hipStream_t stream) {
  const float* query        = (const float*)d_in[0];
  const float* value        = (const float*)d_in[1];
  const float* refp         = (const float*)d_in[2];
  const float* value_proj_w = (const float*)d_in[3];
  const float* value_proj_b = (const float*)d_in[4];
  const float* offsets_w    = (const float*)d_in[5];
  const float* offsets_b    = (const float*)d_in[6];
  const float* attn_w_w     = (const float*)d_in[7];
  const float* attn_w_b     = (const float*)d_in[8];
  const float* out_w        = (const float*)d_in[9];
  const float* out_b        = (const float*)d_in[10];
  float* out = (float*)d_out;

  const int M = M_ROWS; // 21760
  const size_t SZ_BF = (size_t)M * 256 * 2;          // 11,141,120 B
  char* w = (char*)d_ws;
  unsigned short* value_bf = (unsigned short*)w;             // consumed by vp GEMM
  unsigned short* attn_bf  = (unsigned short*)w;             // aliases value_bf (later)
  unsigned short* query_bf = (unsigned short*)(w + SZ_BF);
  unsigned short* v_bf     = (unsigned short*)(w + 2 * SZ_BF);
  float* offaw             = (float*)(w + 3 * SZ_BF);        // M*384 fp32
  char* wts                = w + 3 * SZ_BF + (size_t)M * 384 * 4;
  unsigned short* wt_vp    = (unsigned short*)wts;           // 256*256
  unsigned short* wt_q     = wt_vp + 65536;                  // 384*256
  unsigned short* wt_out   = wt_q + 98304;                   // 256*256
  float* biasq             = (float*)(wt_out + 65536);       // 384

  dim3 blk(256);
  const int n4 = M * 64; // M*256/4
  // prep
  conv_bf16<<<(n4 + 255) / 256, blk, 0, stream>>>(value, value_bf, n4);
  conv_bf16<<<(n4 + 255) / 256, blk, 0, stream>>>(query, query_bf, n4);
  prep_weights<<<898, blk, 0, stream>>>(value_proj_w, offsets_w, attn_w_w, out_w,
                                        offsets_b, attn_w_b,
                                        wt_vp, wt_q, wt_out, biasq);
  // 1) value projection -> bf16 v
  mfma_gemm_lds<unsigned short><<<dim3(4, M / 64), blk, 0, stream>>>(
      value_bf, wt_vp, value_proj_b, v_bf, 256, 256);
  // 2) fused offsets + attn logits (N=384) -> fp32
  mfma_gemm_lds<float><<<dim3(6, M / 64), blk, 0, stream>>>(
      query_bf, wt_q, biasq, offaw, 384, 256);
  // 3) fused softmax + sampling -> bf16 attn (aliases value_bf, already consumed)
  sample_fused_kernel<<<M / 4, blk, 0, stream>>>(v_bf, refp, offaw, attn_bf);
  // 4) output projection -> fp32 out
  mfma_gemm_lds<float><<<dim3(4, M / 64), blk, 0, stream>>>(
      attn_bf, wt_out, out_b, out, 256, 256);
}

// Round 4
// 246.206 us; speedup vs baseline: 2.7740x; 1.0530x over previous
//
#include <hip/hip_runtime.h>
#include <hip/hip_bf16.h>
#include <math.h>

// Problem constants
#define B_ 4
#define NQ 5440          // 64*64 + 32*32 + 16*16 + 8*8
#define M_ROWS (B_ * NQ) // 21760
#define NH 8
#define NL 4
#define NP 4
#define HD 32

typedef __attribute__((ext_vector_type(8))) short bf16x8; // 8 bf16 (4 VGPRs)
typedef __attribute__((ext_vector_type(4))) short bf16x4; // 8 bytes
typedef __attribute__((ext_vector_type(4))) float f32x4;

static __device__ __forceinline__ unsigned short f2bf(float f) {
  union { float f; unsigned u; } v; v.f = f;
  unsigned r = (v.u + 0x7fffu + ((v.u >> 16) & 1u)) >> 16; // RNE
  return (unsigned short)r;
}
static __device__ __forceinline__ float bf2f(unsigned short b) {
  union { unsigned u; float f; } v; v.u = ((unsigned)b) << 16; return v.f;
}

// ---------------- fp32 -> bf16 for value and query in one launch
__global__ __launch_bounds__(256) void conv_bf16_2(
    const float* __restrict__ a, const float* __restrict__ b,
    unsigned short* __restrict__ oa, unsigned short* __restrict__ ob, int n4) {
  int i = blockIdx.x * 256 + threadIdx.x;
  const float* src; unsigned short* dst; int j;
  if (i < n4) { src = a; dst = oa; j = i; }
  else { src = b; dst = ob; j = i - n4; if (j >= n4) return; }
  float4 f = ((const float4*)src)[j];
  bf16x4 o;
  o[0] = f2bf(f.x); o[1] = f2bf(f.y); o[2] = f2bf(f.z); o[3] = f2bf(f.w);
  ((bf16x4*)dst)[j] = o;
}

// ---------------- weight prep: transpose + convert to bf16 W^T[n][k]; concat off+attn
__global__ __launch_bounds__(256) void prep_weights(
    const float* __restrict__ vpw, const float* __restrict__ offw,
    const float* __restrict__ attnw, const float* __restrict__ outw,
    const float* __restrict__ offb, const float* __restrict__ attnb,
    unsigned short* __restrict__ vp_t, unsigned short* __restrict__ q_t,
    unsigned short* __restrict__ out_t, float* __restrict__ biasq) {
  int id = blockIdx.x * 256 + threadIdx.x;
  if (id < 65536) {                       // vp_t[256][256]
    int n = id >> 8, k = id & 255;
    vp_t[id] = f2bf(vpw[k * 256 + n]);
  } else if (id < 163840) {               // q_t[384][256] = [off^T ; attn^T]
    int q = id - 65536; int n = q >> 8, k = q & 255;
    q_t[q] = f2bf(n < 256 ? offw[k * 256 + n] : attnw[k * 128 + (n - 256)]);
  } else if (id < 229376) {               // out_t[256][256]
    int o = id - 163840; int n = o >> 8, k = o & 255;
    out_t[o] = f2bf(outw[k * 256 + n]);
  } else if (id < 229760) {               // biasq[384]
    int j = id - 229376;
    biasq[j] = j < 256 ? offb[j] : attnb[j - 256];
  }
}

static __device__ __forceinline__ void store_c(float* p, float v) { *p = v; }
static __device__ __forceinline__ void store_c(unsigned short* p, float v) { *p = f2bf(v); }

// ---------------- single-barrier full-K bf16 MFMA GEMM (K == 256)
// C[M,N] = A_bf16[M,K] @ Wt_bf16[N,K]^T + bias.  BM=BN=64.
// LDS: 8 stacked m97-style [64][32] tiles per operand (32 KB each). All 16
// global_load_lds_dwordx4 issued up front, ONE barrier, then 32 straight-line MFMAs.
// VT: write C transposed to head-major v (b,h,pix,d) as bf16.
template <typename OUT_T, bool VT>
__global__ __launch_bounds__(256) void mfma_gemm_k256(
    const unsigned short* __restrict__ A, const unsigned short* __restrict__ Wt,
    const float* __restrict__ bias, OUT_T* __restrict__ C, int N) {
  const int K = 256;
  __shared__ unsigned short As[8 * 64 * 32];
  __shared__ unsigned short Bs[8 * 64 * 32];
  const int t = threadIdx.x;
  const int lane = t & 63;
  const int qd = lane >> 4, l16 = lane & 15;
  const int wid = t >> 6;
  const int wm = (wid >> 1) * 32, wn = (wid & 1) * 32;
  const int bm = blockIdx.y * 64, bn = blockIdx.x * 64;

  // staging: thread t covers (row = t>>2, k = (t&3)*8) of tile j; LDS byte = j*4096 + t*16
  const unsigned short* ag = A + (size_t)(bm + (t >> 2)) * K + (t & 3) * 8;
  const unsigned short* bg = Wt + (size_t)(bn + (t >> 2)) * K + (t & 3) * 8;
  unsigned short* as_b = As + (t & 192) * 8; // + j*2048 shorts per tile
  unsigned short* bs_b = Bs + (t & 192) * 8;
#pragma unroll
  for (int j = 0; j < 8; ++j) {
    __builtin_amdgcn_global_load_lds(
        (const __attribute__((address_space(1))) void*)(ag + j * 32),
        (__attribute__((address_space(3))) void*)(as_b + j * 2048), 16, 0, 0);
    __builtin_amdgcn_global_load_lds(
        (const __attribute__((address_space(1))) void*)(bg + j * 32),
        (__attribute__((address_space(3))) void*)(bs_b + j * 2048), 16, 0, 0);
  }
  __syncthreads(); // drains vmcnt; only barrier in the kernel

  f32x4 acc[2][2] = {};
#pragma unroll
  for (int j = 0; j < 8; ++j) {
    const unsigned short* at = As + j * 2048;
    const unsigned short* bt = Bs + j * 2048;
    const bf16x8 af0 = *(const bf16x8*)(at + (wm + l16) * 32 + qd * 8);
    const bf16x8 af1 = *(const bf16x8*)(at + (wm + 16 + l16) * 32 + qd * 8);
    const bf16x8 bf0 = *(const bf16x8*)(bt + (wn + l16) * 32 + qd * 8);
    const bf16x8 bf1 = *(const bf16x8*)(bt + (wn + 16 + l16) * 32 + qd * 8);
    acc[0][0] = __builtin_amdgcn_mfma_f32_16x16x32_bf16(af0, bf0, acc[0][0], 0, 0, 0);
    acc[0][1] = __builtin_amdgcn_mfma_f32_16x16x32_bf16(af0, bf1, acc[0][1], 0, 0, 0);
    acc[1][0] = __builtin_amdgcn_mfma_f32_16x16x32_bf16(af1, bf0, acc[1][0], 0, 0, 0);
    acc[1][1] = __builtin_amdgcn_mfma_f32_16x16x32_bf16(af1, bf1, acc[1][1], 0, 0, 0);
  }
  // C/D layout: col = lane&15, row = (lane>>4)*4 + reg  [m89-verified]
  const int c0 = bn + wn + l16, c1 = bn + wn + 16 + l16;
  const float b0 = bias[c0], b1 = bias[c1];
#pragma unroll
  for (int mi = 0; mi < 2; ++mi) {
#pragma unroll
    for (int r = 0; r < 4; ++r) {
      const int gm = bm + wm + mi * 16 + qd * 4 + r;
      if (VT) {
        // head-major v: ((b*8 + h)*NQ + pix)*32 + d
        const int b = gm / NQ, pix = gm - b * NQ;
        unsigned short* vt = (unsigned short*)C;
        vt[((size_t)(b * NH + (c0 >> 5)) * NQ + pix) * HD + (c0 & 31)] = f2bf(acc[mi][0][r] + b0);
        vt[((size_t)(b * NH + (c1 >> 5)) * NQ + pix) * HD + (c1 & 31)] = f2bf(acc[mi][1][r] + b1);
      } else {
        OUT_T* crow = C + (size_t)gm * N;
        store_c(crow + c0, acc[mi][0][r] + b0);
        store_c(crow + c1, acc[mi][1][r] + b1);
      }
    }
  }
}

// ---------------- Fused softmax + deformable bilinear sampling
// 4 queries/block, 64 threads/query = 8 heads x 8 lanes x 4 dims.
// v head-major: (B, NH, NQ, HD) bf16.  XCD-swizzled block->query map so each
// XCD samples ONE batch's v (2.75 MB < 4 MB per-XCD L2).
__global__ __launch_bounds__(256) void sample_fused_kernel(
    const unsigned short* __restrict__ v, const float* __restrict__ refp,
    const float* __restrict__ offaw, unsigned short* __restrict__ out) {
  __shared__ float s_off[4 * 8 * 36];
  __shared__ float s_aw[4 * 8 * 20];
  const int t = threadIdx.x;
  // XCD swizzle: xcd = blk&7 (round-robin dispatch), batch = xcd>>1
  const int blk = blockIdx.x;
  const int b = (blk & 7) >> 1;
  const int q0loc = ((blk >> 3) * 2 + (blk & 1)) * 4; // [0, 5440) step 4
  const int q0 = b * NQ + q0loc;

  { // stage offsets: 4 queries x 256 floats, padded (stride 36) scatter
    const int ql = t >> 6, c = (t & 63) * 4, h = c >> 5, r = c & 31;
    const float4 f = *(const float4*)(offaw + (size_t)(q0 + ql) * 384 + c);
    *(float4*)&s_off[ql * 288 + h * 36 + r] = f;
  }
  if (t < 128) { // stage attn logits: 4 x 128, stride 20
    const int ql = t >> 5, c = (t & 31) * 4, h = c >> 4, r = c & 15;
    const float4 f = *(const float4*)(offaw + (size_t)(q0 + ql) * 384 + 256 + c);
    *(float4*)&s_aw[ql * 160 + h * 20 + r] = f;
  }
  __syncthreads();
  if (t < 32) { // softmax: 32 groups of 16
    float* p = s_aw + (t >> 3) * 160 + (t & 7) * 20;
    float m = -1e30f;
#pragma unroll
    for (int j = 0; j < 16; ++j) m = fmaxf(m, p[j]);
    float e[16]; float s = 0.f;
#pragma unroll
    for (int j = 0; j < 16; ++j) { e[j] = __expf(p[j] - m); s += e[j]; }
    const float inv = 1.f / s;
#pragma unroll
    for (int j = 0; j < 16; ++j) p[j] = e[j] * inv;
  }
  __syncthreads();

  const int ql = t >> 6;
  const int bq = q0 + ql;
  const int lane = t & 63;
  const int h  = lane >> 3;
  const int d4 = (lane & 7) * 4;
  const float* so = s_off + ql * 288 + h * 36;
  const float* sa = s_aw + ql * 160 + h * 20;

  const int HS[NL]      = {64, 32, 16, 8};
  const int LVL_OFF[NL] = {0, 4096, 5120, 5376};

  f32x4 acc = {0.f, 0.f, 0.f, 0.f};
#pragma unroll
  for (int l = 0; l < NL; ++l) {
    const int H = HS[l], W = HS[l];
    const float rx = refp[(size_t)bq * 8 + l * 2 + 0];
    const float ry = refp[(size_t)bq * 8 + l * 2 + 1];
    // head-major: ((b*NH+h)*NQ + lvl_off + pix)*HD + d
    const unsigned short* vb =
        v + ((size_t)(b * NH + h) * NQ + LVL_OFF[l]) * HD + d4;
#pragma unroll
    for (int p = 0; p < NP; ++p) {
      const float ox = so[l * 8 + p * 2 + 0];
      const float oy = so[l * 8 + p * 2 + 1];
      const float a  = sa[l * 4 + p];
      const float px = rx * (float)W + ox - 0.5f;
      const float py = ry * (float)H + oy - 0.5f;
      const float x0f = floorf(px), y0f = floorf(py);
      const int x0 = (int)x0f, y0 = (int)y0f;
      const int x1 = x0 + 1, y1 = y0 + 1;
      const float wx = px - x0f, wy = py - y0f;
      const bool vx0 = (x0 >= 0) & (x0 < W);
      const bool vx1 = (x1 >= 0) & (x1 < W);
      const bool vy0 = (y0 >= 0) & (y0 < H);
      const bool vy1 = (y1 >= 0) & (y1 < H);
      f32x4 s = {0.f, 0.f, 0.f, 0.f};
      if (vy0) {
        const unsigned short* row = vb + (size_t)(y0 * W) * HD;
        if (vx0) {
          const bf16x4 c = *(const bf16x4*)(row + (size_t)x0 * HD);
          f32x4 cf = {bf2f((unsigned short)c[0]), bf2f((unsigned short)c[1]),
                      bf2f((unsigned short)c[2]), bf2f((unsigned short)c[3])};
          s += ((1.f - wx) * (1.f - wy)) * cf;
        }
        if (vx1) {
          const bf16x4 c = *(const bf16x4*)(row + (size_t)x1 * HD);
          f32x4 cf = {bf2f((unsigned short)c[0]), bf2f((unsigned short)c[1]),
                      bf2f((unsigned short)c[2]), bf2f((unsigned short)c[3])};
          s += (wx * (1.f - wy)) * cf;
        }
      }
      if (vy1) {
        const unsigned short* row = vb + (size_t)(y1 * W) * HD;
        if (vx0) {
          const bf16x4 c = *(const bf16x4*)(row + (size_t)x0 * HD);
          f32x4 cf = {bf2f((unsigned short)c[0]), bf2f((unsigned short)c[1]),
                      bf2f((unsigned short)c[2]), bf2f((unsigned short)c[3])};
          s += ((1.f - wx) * wy) * cf;
        }
        if (vx1) {
          const bf16x4 c = *(const bf16x4*)(row + (size_t)x1 * HD);
          f32x4 cf = {bf2f((unsigned short)c[0]), bf2f((unsigned short)c[1]),
                      bf2f((unsigned short)c[2]), bf2f((unsigned short)c[3])};
          s += (wx * wy) * cf;
        }
      }
      acc += a * s;
    }
  }
  unsigned short* op = out + (size_t)bq * 256 + h * HD + d4;
  bf16x4 ov;
  ov[0] = f2bf(acc[0]); ov[1] = f2bf(acc[1]);
  ov[2] = f2bf(acc[2]); ov[3] = f2bf(acc[3]);
  *(bf16x4*)op = ov;
}

extern "C" void kernel_launch(void* const* d_in, const int* in_sizes, int n_in,
                              void* d_out, int out_size, void* d_ws, size_t ws_size,
                              hipStream_t stream) {
  const float* query        = (const float*)d_in[0];
  const float* value        = (const float*)d_in[1];
  const float* refp         = (const float*)d_in[2];
  const float* value_proj_w = (const float*)d_in[3];
  const float* value_proj_b = (const float*)d_in[4];
  const float* offsets_w    = (const float*)d_in[5];
  const float* offsets_b    = (const float*)d_in[6];
  const float* attn_w_w     = (const float*)d_in[7];
  const float* attn_w_b     = (const float*)d_in[8];
  const float* out_w        = (const float*)d_in[9];
  const float* out_b        = (const float*)d_in[10];
  float* out = (float*)d_out;

  const int M = M_ROWS; // 21760
  const size_t SZ_BF = (size_t)M * 256 * 2;
  char* w = (char*)d_ws;
  unsigned short* value_bf = (unsigned short*)w;             // consumed by vp GEMM
  unsigned short* attn_bf  = (unsigned short*)w;             // aliases value_bf
  unsigned short* query_bf = (unsigned short*)(w + SZ_BF);
  unsigned short* v_bf     = (unsigned short*)(w + 2 * SZ_BF); // head-major
  float* offaw             = (float*)(w + 3 * SZ_BF);        // M*384 fp32
  char* wts                = w + 3 * SZ_BF + (size_t)M * 384 * 4;
  unsigned short* wt_vp    = (unsigned short*)wts;           // 256*256
  unsigned short* wt_q     = wt_vp + 65536;                  // 384*256
  unsigned short* wt_out   = wt_q + 98304;                   // 256*256
  float* biasq             = (float*)(wt_out + 65536);       // 384

  dim3 blk(256);
  const int n4 = M * 64;
  conv_bf16_2<<<(2 * n4 + 255) / 256, blk, 0, stream>>>(value, query, value_bf, query_bf, n4);
  prep_weights<<<898, blk, 0, stream>>>(value_proj_w, offsets_w, attn_w_w, out_w,
                                        offsets_b, attn_w_b,
                                        wt_vp, wt_q, wt_out, biasq);
  // 1) value projection -> head-major bf16 v
  mfma_gemm_k256<unsigned short, true><<<dim3(4, M / 64), blk, 0, stream>>>(
      value_bf, wt_vp, value_proj_b, v_bf, 256);
  // 2) fused offsets + attn logits (N=384) -> fp32
  mfma_gemm_k256<float, false><<<dim3(6, M / 64), blk, 0, stream>>>(
      query_bf, wt_q, biasq, offaw, 384);
  // 3) fused softmax + sampling (XCD-swizzled) -> bf16
  sample_fused_kernel<<<M / 4, blk, 0, stream>>>(v_bf, refp, offaw, attn_bf);
  // 4) output projection -> fp32 out
  mfma_gemm_k256<float, false><<<dim3(4, M / 64), blk, 0, stream>>>(
      attn_bf, wt_out, out_b, out, 256);
}

// Round 5
// 222.734 us; speedup vs baseline: 3.0664x; 1.1054x over previous
//
#include <hip/hip_runtime.h>
#include <hip/hip_bf16.h>
#include <math.h>

// Problem constants
#define B_ 4
#define NQ 5440          // 64*64 + 32*32 + 16*16 + 8*8
#define M_ROWS (B_ * NQ) // 21760
#define NH 8
#define NL 4
#define NP 4
#define HD 32

typedef __attribute__((ext_vector_type(8))) short bf16x8; // 8 bf16 (4 VGPRs)
typedef __attribute__((ext_vector_type(4))) short bf16x4; // 8 bytes
typedef __attribute__((ext_vector_type(4))) float f32x4;

static __device__ __forceinline__ unsigned short f2bf(float f) {
  union { float f; unsigned u; } v; v.f = f;
  unsigned r = (v.u + 0x7fffu + ((v.u >> 16) & 1u)) >> 16; // RNE
  return (unsigned short)r;
}
static __device__ __forceinline__ float bits2f(unsigned u) {
  union { unsigned u; float f; } v; v.u = u; return v.f;
}

// ---------------- merged prep: fp32->bf16 of value+query, weight transpose+convert
__global__ __launch_bounds__(256) void prep_all(
    const float* __restrict__ value, const float* __restrict__ query,
    unsigned short* __restrict__ value_bf, unsigned short* __restrict__ query_bf,
    const float* __restrict__ vpw, const float* __restrict__ offw,
    const float* __restrict__ attnw, const float* __restrict__ outw,
    const float* __restrict__ offb, const float* __restrict__ attnb,
    unsigned short* __restrict__ vp_t, unsigned short* __restrict__ q_t,
    unsigned short* __restrict__ out_t, float* __restrict__ biasq, int n4) {
  int id = blockIdx.x * 256 + threadIdx.x;
  if (id < 2 * n4) { // conversion part
    const float* src; unsigned short* dst; int j;
    if (id < n4) { src = value; dst = value_bf; j = id; }
    else { src = query; dst = query_bf; j = id - n4; }
    float4 f = ((const float4*)src)[j];
    bf16x4 o;
    o[0] = f2bf(f.x); o[1] = f2bf(f.y); o[2] = f2bf(f.z); o[3] = f2bf(f.w);
    ((bf16x4*)dst)[j] = o;
    return;
  }
  int w = id - 2 * n4;
  if (w < 65536) {                        // vp_t[256][256]
    int n = w >> 8, k = w & 255;
    vp_t[w] = f2bf(vpw[k * 256 + n]);
  } else if (w < 163840) {                // q_t[384][256] = [off^T ; attn^T]
    int q = w - 65536; int n = q >> 8, k = q & 255;
    q_t[q] = f2bf(n < 256 ? offw[k * 256 + n] : attnw[k * 128 + (n - 256)]);
  } else if (w < 229376) {                // out_t[256][256]
    int o = w - 163840; int n = o >> 8, k = o & 255;
    out_t[o] = f2bf(outw[k * 256 + n]);
  } else if (w < 229760) {                // biasq[384]
    int j = w - 229376;
    biasq[j] = j < 256 ? offb[j] : attnb[j - 256];
  }
}

// ---------------- no-LDS, no-barrier direct MFMA GEMM core (K=256)
// Fragments loaded straight from global (A tile fits L1, weights L2-hot).
static __device__ __forceinline__ void gemm_core(
    const unsigned short* __restrict__ A, const unsigned short* __restrict__ Wt,
    int bm, int bn, int wm, int wn, int l16, int qd, f32x4 acc[2][2]) {
  const unsigned short* ar0 = A + (size_t)(bm + wm + l16) * 256 + qd * 8;
  const unsigned short* ar1 = ar0 + 16 * 256;
  const unsigned short* br0 = Wt + (size_t)(bn + wn + l16) * 256 + qd * 8;
  const unsigned short* br1 = br0 + 16 * 256;
#pragma unroll
  for (int j = 0; j < 8; ++j) {
    const bf16x8 af0 = *(const bf16x8*)(ar0 + j * 32);
    const bf16x8 af1 = *(const bf16x8*)(ar1 + j * 32);
    const bf16x8 bf0 = *(const bf16x8*)(br0 + j * 32);
    const bf16x8 bf1 = *(const bf16x8*)(br1 + j * 32);
    acc[0][0] = __builtin_amdgcn_mfma_f32_16x16x32_bf16(af0, bf0, acc[0][0], 0, 0, 0);
    acc[0][1] = __builtin_amdgcn_mfma_f32_16x16x32_bf16(af0, bf1, acc[0][1], 0, 0, 0);
    acc[1][0] = __builtin_amdgcn_mfma_f32_16x16x32_bf16(af1, bf0, acc[1][0], 0, 0, 0);
    acc[1][1] = __builtin_amdgcn_mfma_f32_16x16x32_bf16(af1, bf1, acc[1][1], 0, 0, 0);
  }
}

// merged GEMM1 (value proj -> head-major bf16 v) + GEMM2 (offsets+logits -> fp32)
__global__ __launch_bounds__(256) void gemm12_kernel(
    const unsigned short* __restrict__ valbf, const unsigned short* __restrict__ qrybf,
    const unsigned short* __restrict__ wt_vp, const unsigned short* __restrict__ wt_q,
    const float* __restrict__ vp_b, const float* __restrict__ biasq,
    unsigned short* __restrict__ v_bf, float* __restrict__ offaw) {
  const int t = threadIdx.x;
  const int lane = t & 63, wid = t >> 6;
  const int qd = lane >> 4, l16 = lane & 15;
  const int wm = (wid >> 1) * 32, wn = (wid & 1) * 32;
  const int bm = blockIdx.y * 64;
  const int bx = blockIdx.x;
  const bool isv = bx < 4;
  const int bn = isv ? bx * 64 : (bx - 4) * 64;

  f32x4 acc[2][2] = {};
  gemm_core(isv ? valbf : qrybf, isv ? wt_vp : wt_q, bm, bn, wm, wn, l16, qd, acc);

  // C/D layout: col = lane&15, row = (lane>>4)*4 + reg  [m89-verified]
  const int c0 = bn + wn + l16, c1 = bn + wn + 16 + l16;
  if (isv) {
    const float b0 = vp_b[c0], b1 = vp_b[c1];
#pragma unroll
    for (int mi = 0; mi < 2; ++mi)
#pragma unroll
      for (int r = 0; r < 4; ++r) {
        const int gm = bm + wm + mi * 16 + qd * 4 + r;
        const int b = gm / NQ, pix = gm - b * NQ;
        v_bf[((size_t)(b * NH + (c0 >> 5)) * NQ + pix) * HD + (c0 & 31)] = f2bf(acc[mi][0][r] + b0);
        v_bf[((size_t)(b * NH + (c1 >> 5)) * NQ + pix) * HD + (c1 & 31)] = f2bf(acc[mi][1][r] + b1);
      }
  } else {
    const float b0 = biasq[c0], b1 = biasq[c1];
#pragma unroll
    for (int mi = 0; mi < 2; ++mi)
#pragma unroll
      for (int r = 0; r < 4; ++r) {
        const int gm = bm + wm + mi * 16 + qd * 4 + r;
        float* crow = offaw + (size_t)gm * 384;
        crow[c0] = acc[mi][0][r] + b0;
        crow[c1] = acc[mi][1][r] + b1;
      }
  }
}

// GEMM3: out = attn_bf @ out_w^T + out_b (fp32 out)
__global__ __launch_bounds__(256) void gemm_out_kernel(
    const unsigned short* __restrict__ attn_bf, const unsigned short* __restrict__ wt_out,
    const float* __restrict__ out_b, float* __restrict__ out) {
  const int t = threadIdx.x;
  const int lane = t & 63, wid = t >> 6;
  const int qd = lane >> 4, l16 = lane & 15;
  const int wm = (wid >> 1) * 32, wn = (wid & 1) * 32;
  const int bm = blockIdx.y * 64, bn = blockIdx.x * 64;
  f32x4 acc[2][2] = {};
  gemm_core(attn_bf, wt_out, bm, bn, wm, wn, l16, qd, acc);
  const int c0 = bn + wn + l16, c1 = bn + wn + 16 + l16;
  const float b0 = out_b[c0], b1 = out_b[c1];
#pragma unroll
  for (int mi = 0; mi < 2; ++mi)
#pragma unroll
    for (int r = 0; r < 4; ++r) {
      const int gm = bm + wm + mi * 16 + qd * 4 + r;
      float* crow = out + (size_t)gm * 256;
      crow[c0] = acc[mi][0][r] + b0;
      crow[c1] = acc[mi][1][r] + b1;
    }
}

// ---------------- Fused softmax + precompute-then-gather deformable sampling
// 8 queries/block (256 threads). Phases:
//  1. stage offaw rows [8][384] + refp [8][8] into LDS
//  2. softmax (64 groups of 16), in place
//  3. tuple phase: 256 threads compute (q,h,p) corner byte-offsets (clamped)
//     and folded weights (bilinear*attn, 0 when invalid) -> LDS [p][qh]
//  4. gather: lane=(q,h,d8); per point 2 ds_read_b128 + 4 dwordx4 gathers + FMA
__global__ __launch_bounds__(256) void sample_fused_kernel(
    const unsigned short* __restrict__ v, const float* __restrict__ refp,
    const float* __restrict__ offaw, unsigned short* __restrict__ out) {
  __shared__ float s_off[8 * 384];          // 12 KB (cols 256..384 = logits)
  __shared__ float s_ref[64];
  __shared__ unsigned s_offs[16 * 64 * 4];  // 16 KB, [p][qh][c]
  __shared__ float s_wts[16 * 64 * 4];      // 16 KB
  const int t = threadIdx.x;
  // XCD swizzle: xcd = blk&7, batch = xcd>>1 (per-batch v is 2.75 MB < 4 MB L2/XCD)
  const int blk = blockIdx.x;
  const int b = (blk & 7) >> 1;
  const int q0loc = ((blk >> 3) * 2 + (blk & 1)) * 8;
  const int q0 = b * NQ + q0loc; // first global row

  { // phase 1: stage
    const float4* src = (const float4*)(offaw + (size_t)q0 * 384);
    float4* dst = (float4*)s_off;
#pragma unroll
    for (int i = 0; i < 3; ++i) dst[t + i * 256] = src[t + i * 256];
    if (t < 64) s_ref[t] = refp[(size_t)q0 * 8 + t];
  }
  __syncthreads();
  if (t < 64) { // phase 2: softmax, 64 groups of 16
    float* p = s_off + (t >> 3) * 384 + 256 + (t & 7) * 16;
    float m = -1e30f;
#pragma unroll
    for (int j = 0; j < 16; ++j) m = fmaxf(m, p[j]);
    float e[16]; float s = 0.f;
#pragma unroll
    for (int j = 0; j < 16; ++j) { e[j] = __expf(p[j] - m); s += e[j]; }
    const float inv = 1.f / s;
#pragma unroll
    for (int j = 0; j < 16; ++j) p[j] = e[j] * inv;
  }
  __syncthreads();
  { // phase 3: tuples. t -> qh = t&63 (q=qh>>3,h=qh&7), level l = t>>6
    const int qh = t & 63, q = qh >> 3, h = qh & 7, l = t >> 6;
    const int HS[NL]      = {64, 32, 16, 8};
    const int LVL_OFF[NL] = {0, 4096, 5120, 5376};
    const int H = HS[l], W = HS[l];
    const float rx = s_ref[q * 8 + l * 2 + 0];
    const float ry = s_ref[q * 8 + l * 2 + 1];
    // byte offset base for this (b,h,level): ((b*8+h)*NQ + lvl)*64
    const unsigned vbase = (unsigned)(((b * NH + h) * NQ + LVL_OFF[l]) * 64);
#pragma unroll
    for (int pp = 0; pp < 4; ++pp) {
      const int p = l * 4 + pp;
      const float ox = s_off[q * 384 + h * 32 + l * 8 + pp * 2 + 0];
      const float oy = s_off[q * 384 + h * 32 + l * 8 + pp * 2 + 1];
      const float a  = s_off[q * 384 + 256 + h * 16 + p];
      const float px = rx * (float)W + ox - 0.5f;
      const float py = ry * (float)H + oy - 0.5f;
      const float x0f = floorf(px), y0f = floorf(py);
      const int x0 = (int)x0f, y0 = (int)y0f;
      const int x1 = x0 + 1, y1 = y0 + 1;
      const float wx = px - x0f, wy = py - y0f;
      const float m_x0 = (x0 >= 0 && x0 < W) ? 1.f : 0.f;
      const float m_x1 = (x1 >= 0 && x1 < W) ? 1.f : 0.f;
      const float m_y0 = (y0 >= 0 && y0 < H) ? 1.f : 0.f;
      const float m_y1 = (y1 >= 0 && y1 < H) ? 1.f : 0.f;
      const int cx0 = min(max(x0, 0), W - 1), cx1 = min(max(x1, 0), W - 1);
      const int cy0 = min(max(y0, 0), H - 1), cy1 = min(max(y1, 0), H - 1);
      const int ti = (p * 64 + qh) * 4;
      uint4 o4;
      o4.x = vbase + (unsigned)((cy0 * W + cx0) * 64);
      o4.y = vbase + (unsigned)((cy0 * W + cx1) * 64);
      o4.z = vbase + (unsigned)((cy1 * W + cx0) * 64);
      o4.w = vbase + (unsigned)((cy1 * W + cx1) * 64);
      float4 w4;
      w4.x = a * (1.f - wx) * (1.f - wy) * m_x0 * m_y0;
      w4.y = a * wx * (1.f - wy) * m_x1 * m_y0;
      w4.z = a * (1.f - wx) * wy * m_x0 * m_y1;
      w4.w = a * wx * wy * m_x1 * m_y1;
      *(uint4*)&s_offs[ti] = o4;
      *(float4*)&s_wts[ti] = w4;
    }
  }
  __syncthreads();
  // phase 4: gather. wave = 2 queries; lane = q1*32 + h*4 + d8
  const int lane = t & 63, wave = t >> 6;
  const int qloc = wave * 2 + (lane >> 5);
  const int h = (lane >> 2) & 7, d8 = lane & 3;
  const int tqh = qloc * 8 + h;
  const char* vB = (const char*)v;
  const int dof = d8 * 16; // byte offset of this lane's 8-dim chunk
  float acc[8] = {};
#pragma unroll 4
  for (int p = 0; p < 16; ++p) {
    const uint4  o4 = *(const uint4*)&s_offs[(p * 64 + tqh) * 4];
    const float4 w4 = *(const float4*)&s_wts[(p * 64 + tqh) * 4];
    const unsigned off[4] = {o4.x, o4.y, o4.z, o4.w};
    const float wt[4] = {w4.x, w4.y, w4.z, w4.w};
#pragma unroll
    for (int c = 0; c < 4; ++c) {
      union { bf16x8 v8; unsigned u[4]; } cc;
      cc.v8 = *(const bf16x8*)(vB + off[c] + dof);
      const float w = wt[c];
#pragma unroll
      for (int k = 0; k < 4; ++k) {
        acc[2 * k]     += w * bits2f(cc.u[k] << 16);
        acc[2 * k + 1] += w * bits2f(cc.u[k] & 0xffff0000u);
      }
    }
  }
  const int bq = q0 + qloc;
  bf16x8 ov;
#pragma unroll
  for (int k = 0; k < 8; ++k) ov[k] = (short)f2bf(acc[k]);
  *(bf16x8*)(out + (size_t)bq * 256 + h * HD + d8 * 8) = ov;
}

extern "C" void kernel_launch(void* const* d_in, const int* in_sizes, int n_in,
                              void* d_out, int out_size, void* d_ws, size_t ws_size,
                              hipStream_t stream) {
  const float* query        = (const float*)d_in[0];
  const float* value        = (const float*)d_in[1];
  const float* refp         = (const float*)d_in[2];
  const float* value_proj_w = (const float*)d_in[3];
  const float* value_proj_b = (const float*)d_in[4];
  const float* offsets_w    = (const float*)d_in[5];
  const float* offsets_b    = (const float*)d_in[6];
  const float* attn_w_w     = (const float*)d_in[7];
  const float* attn_w_b     = (const float*)d_in[8];
  const float* out_w        = (const float*)d_in[9];
  const float* out_b        = (const float*)d_in[10];
  float* out = (float*)d_out;

  const int M = M_ROWS; // 21760
  const size_t SZ_BF = (size_t)M * 256 * 2;
  char* w = (char*)d_ws;
  unsigned short* value_bf = (unsigned short*)w;               // consumed by gemm12
  unsigned short* attn_bf  = (unsigned short*)w;               // aliases value_bf
  unsigned short* query_bf = (unsigned short*)(w + SZ_BF);
  unsigned short* v_bf     = (unsigned short*)(w + 2 * SZ_BF); // head-major
  float* offaw             = (float*)(w + 3 * SZ_BF);          // M*384 fp32
  char* wts                = w + 3 * SZ_BF + (size_t)M * 384 * 4;
  unsigned short* wt_vp    = (unsigned short*)wts;             // 256*256
  unsigned short* wt_q     = wt_vp + 65536;                    // 384*256
  unsigned short* wt_out   = wt_q + 98304;                     // 256*256
  float* biasq             = (float*)(wt_out + 65536);         // 384

  dim3 blk(256);
  const int n4 = M * 64;
  const int prep_blocks = (2 * n4 + 229760 + 255) / 256;
  prep_all<<<prep_blocks, blk, 0, stream>>>(
      value, query, value_bf, query_bf,
      value_proj_w, offsets_w, attn_w_w, out_w, offsets_b, attn_w_b,
      wt_vp, wt_q, wt_out, biasq, n4);
  // merged value-proj (cols 0-3, head-major v) + offsets/logits (cols 4-9)
  gemm12_kernel<<<dim3(10, M / 64), blk, 0, stream>>>(
      value_bf, query_bf, wt_vp, wt_q, value_proj_b, biasq, v_bf, offaw);
  // fused softmax + sampling (XCD-swizzled) -> bf16
  sample_fused_kernel<<<M / 8, blk, 0, stream>>>(v_bf, refp, offaw, attn_bf);
  // output projection -> fp32 out
  gemm_out_kernel<<<dim3(4, M / 64), blk, 0, stream>>>(attn_bf, wt_out, out_b, out);
}